// Round 6
// baseline (2419.457 us; speedup 1.0000x reference)
//
#include <hip/hip_runtime.h>
#include <math.h>

#define BB 64
#define LL 200
#define DD 128
#define MM 50
#define NQ 10000
#define NPOS (BB * LL)   // 12800
#define LC 20            // scan chunk length
#define NC 10            // number of chunks (LC*NC == LL)

// Diagnostic amplification factors (idempotent kernels only).
#define REP_WEA   16
#define REP_SCANA 16
#define REP_SCANC 4
#define REP_FP    16

// ---------------------------------------------------------------------------
// Kernel 1: gather k,v; compute w = softmax(k@Mk^T), e = sigmoid(v@e_W^T+e_b),
//           a = tanh(v@a_W^T+a_b). One block = 16 positions, 256 threads.
// (R2 version + rep loop)
// ---------------------------------------------------------------------------
__global__ __launch_bounds__(256) void k_wea(
    const int* __restrict__ q, const int* __restrict__ r,
    const float* __restrict__ k_emb, const float* __restrict__ v_emb,
    const float* __restrict__ Mk,
    const float* __restrict__ e_W, const float* __restrict__ e_b,
    const float* __restrict__ a_W, const float* __restrict__ a_b,
    float* __restrict__ w_ws, float* __restrict__ e_ws, float* __restrict__ a_ws,
    int rep)
{
    __shared__ float k_lds[16][DD];
    __shared__ float v_lds[16][DD];
    __shared__ float lg[16][MM];

    const int tid = threadIdx.x;
    const int p0  = blockIdx.x * 16;

    for (int rp = 0; rp < rep; ++rp) {

    // ---- stage k, v rows into LDS (float4-coalesced) ----
    #pragma unroll
    for (int rr = 0; rr < 2; ++rr) {
        int idx = rr * 256 + tid;         // 0..511
        int pos = idx >> 5;               // 16 positions x 32 float4
        int c4  = idx & 31;
        int gp  = p0 + pos;
        int qi  = q[gp];
        int xi  = qi + NQ * r[gp];
        float4 kv = *(const float4*)(k_emb + (size_t)qi * DD + c4 * 4);
        float4 vv = *(const float4*)(v_emb + (size_t)xi * DD + c4 * 4);
        *(float4*)(&k_lds[pos][c4 * 4]) = kv;
        *(float4*)(&v_lds[pos][c4 * 4]) = vv;
    }
    __syncthreads();

    // ---- logits: 16 pos x 50 m dots of length 128 ----
    for (int j = tid; j < 16 * MM; j += 256) {
        int pos = j / MM;
        int m   = j - pos * MM;
        const float* mk = Mk + m * DD;
        float acc = 0.f;
        #pragma unroll 4
        for (int jj = 0; jj < DD; ++jj)
            acc = fmaf(k_lds[pos][jj], mk[jj], acc);
        lg[pos][m] = acc;
    }
    __syncthreads();

    // ---- softmax over M=50, one thread per position ----
    if (tid < 16) {
        int pos = tid;
        float mx = -INFINITY;
        for (int m = 0; m < MM; ++m) mx = fmaxf(mx, lg[pos][m]);
        float s = 0.f;
        for (int m = 0; m < MM; ++m) {
            float e_ = expf(lg[pos][m] - mx);
            lg[pos][m] = e_;
            s += e_;
        }
        float inv = 1.f / s;
        float* wout = w_ws + (size_t)(p0 + pos) * MM;
        for (int m = 0; m < MM; ++m) wout[m] = lg[pos][m] * inv;
    }

    // ---- e, a: thread (i = tid&127) x (half = tid>>7 -> 8 positions) ----
    const int i    = tid & 127;
    const int half = tid >> 7;
    float acc_e[8], acc_a[8];
    const float eb = e_b[i];
    const float ab = a_b[i];
    #pragma unroll
    for (int p = 0; p < 8; ++p) { acc_e[p] = eb; acc_a[p] = ab; }

    const float4* ew = (const float4*)(e_W + (size_t)i * DD);
    const float4* aw = (const float4*)(a_W + (size_t)i * DD);
    #pragma unroll 4
    for (int j4 = 0; j4 < 32; ++j4) {
        float4 we = ew[j4];
        float4 wa = aw[j4];
        #pragma unroll
        for (int p = 0; p < 8; ++p) {
            const float* vp = &v_lds[half * 8 + p][j4 * 4];
            acc_e[p] = fmaf(we.x, vp[0], acc_e[p]);
            acc_e[p] = fmaf(we.y, vp[1], acc_e[p]);
            acc_e[p] = fmaf(we.z, vp[2], acc_e[p]);
            acc_e[p] = fmaf(we.w, vp[3], acc_e[p]);
            acc_a[p] = fmaf(wa.x, vp[0], acc_a[p]);
            acc_a[p] = fmaf(wa.y, vp[1], acc_a[p]);
            acc_a[p] = fmaf(wa.z, vp[2], acc_a[p]);
            acc_a[p] = fmaf(wa.w, vp[3], acc_a[p]);
        }
    }
    #pragma unroll
    for (int p = 0; p < 8; ++p) {
        int gp = p0 + half * 8 + p;
        e_ws[(size_t)gp * DD + i] = 1.f / (1.f + expf(-acc_e[p]));
        a_ws[(size_t)gp * DD + i] = tanhf(acc_a[p]);
    }
    __syncthreads();   // protect LDS before next rep restages
    }
}

// ---------------------------------------------------------------------------
// Kernel 2a: per (b, chunk) affine composite S_out = A*S_in + B per (m,d).
// ---------------------------------------------------------------------------
__global__ __launch_bounds__(512) void k_scanA(
    const float* __restrict__ w_ws, const float* __restrict__ e_ws,
    const float* __restrict__ a_ws,
    float* __restrict__ A_ws, float* __restrict__ B_ws, int rep)
{
    __shared__ float w_lds[LC * MM];   // 4 KB

    const int b   = blockIdx.x / NC;
    const int c   = blockIdx.x % NC;
    const int tid = threadIdx.x;
    const int d   = tid & 127;
    const int g   = tid >> 7;
    int moff = g * 13; if (g == 3) moff = 38;
    const int mcnt = (g < 2) ? 13 : 12;

    for (int rp = 0; rp < rep; ++rp) {

    const float* wsrc = w_ws + ((size_t)b * LL + c * LC) * MM;  // contiguous
    for (int idx = tid; idx < LC * MM; idx += 512) w_lds[idx] = wsrc[idx];
    __syncthreads();

    float A[13], Bv[13];
    #pragma unroll
    for (int mi = 0; mi < 13; ++mi) { A[mi] = 1.f; Bv[mi] = 0.f; }

    for (int ll = 0; ll < LC; ++ll) {
        const int gp = b * LL + c * LC + ll;
        const float e = e_ws[(size_t)gp * DD + d];
        const float a = a_ws[(size_t)gp * DD + d];
        const float* wl = w_lds + ll * MM + moff;
        #pragma unroll
        for (int mi = 0; mi < 13; ++mi) {
            if (mi < mcnt) {
                float w_ = wl[mi];
                float cc = fmaf(-w_, e, 1.f);
                A[mi] *= cc;
                Bv[mi] = fmaf(Bv[mi], cc, w_ * a);
            }
        }
    }

    float* Ao = A_ws + ((size_t)b * NC + c) * MM * DD + (size_t)moff * DD + d;
    float* Bo = B_ws + ((size_t)b * NC + c) * MM * DD + (size_t)moff * DD + d;
    #pragma unroll
    for (int mi = 0; mi < 13; ++mi) {
        if (mi < mcnt) { Ao[mi * DD] = A[mi]; Bo[mi * DD] = Bv[mi]; }
    }
    __syncthreads();
    }
}

// ---------------------------------------------------------------------------
// Kernel 2b: sequential composition over chunks; writes chunk ENTRY states
// in-place over A_ws. One thread per (b,m,d).  NOT idempotent -> never amplified.
// ---------------------------------------------------------------------------
__global__ __launch_bounds__(256) void k_scanB(
    const float* __restrict__ Mv0,
    float* __restrict__ A_ws,            // in: A, out: Sentry
    const float* __restrict__ B_ws)
{
    const int g  = blockIdx.x * 256 + threadIdx.x;   // 0 .. B*M*D-1
    const int d  = g & (DD - 1);
    const int md = g >> 7;
    const int m  = md % MM;
    const int b  = md / MM;

    float S = Mv0[m * DD + d];
    const size_t base = ((size_t)b * NC * MM + m) * DD + d;
    #pragma unroll
    for (int c = 0; c < NC; ++c) {
        const size_t off = base + (size_t)c * MM * DD;
        const float Ac = A_ws[off];
        const float Bc = B_ws[off];
        A_ws[off] = S;                     // entry state of chunk c
        S = fmaf(Ac, S, Bc);
    }
}

// ---------------------------------------------------------------------------
// Kernel 2c: replay the scan per (b, chunk) from its entry state; writes all
// Mv states and read[b,l,d] = sum_m w*Mv_pre.
// ---------------------------------------------------------------------------
__global__ __launch_bounds__(512) void k_scanC(
    const float* __restrict__ Sentry,     // == A_ws after k_scanB
    const float* __restrict__ w_ws, const float* __restrict__ e_ws,
    const float* __restrict__ a_ws,
    float* __restrict__ read_ws, float* __restrict__ out_Mv, int rep)
{
    __shared__ float w_lds[LC * MM];      // 4 KB
    __shared__ float red[2][4][DD];       // 4 KB

    const int b   = blockIdx.x / NC;
    const int c   = blockIdx.x % NC;
    const int tid = threadIdx.x;
    const int d   = tid & 127;
    const int g   = tid >> 7;
    int moff = g * 13; if (g == 3) moff = 38;
    const int mcnt = (g < 2) ? 13 : 12;

    for (int rp = 0; rp < rep; ++rp) {

    const float* wsrc = w_ws + ((size_t)b * LL + c * LC) * MM;
    for (int idx = tid; idx < LC * MM; idx += 512) w_lds[idx] = wsrc[idx];

    float S[13];
    const float* Sp = Sentry + ((size_t)b * NC + c) * MM * DD + (size_t)moff * DD + d;
    #pragma unroll
    for (int mi = 0; mi < 13; ++mi)
        if (mi < mcnt) S[mi] = Sp[mi * DD];

    float* outb = out_Mv + (size_t)b * (LL + 1) * MM * DD;
    if (c == 0) {
        #pragma unroll
        for (int mi = 0; mi < 13; ++mi)
            if (mi < mcnt) outb[(moff + mi) * DD + d] = S[mi];  // init state
    }
    __syncthreads();

    for (int ll = 0; ll < LC; ++ll) {
        const int l  = c * LC + ll;
        const int gp = b * LL + l;
        const float e = e_ws[(size_t)gp * DD + d];
        const float a = a_ws[(size_t)gp * DD + d];
        const float* wl = w_lds + ll * MM + moff;

        float racc = 0.f;
        float* o = outb + (size_t)(l + 1) * MM * DD + d;
        #pragma unroll
        for (int mi = 0; mi < 13; ++mi) {
            if (mi < mcnt) {
                float w_ = wl[mi];
                racc = fmaf(w_, S[mi], racc);                // pre-update read
                S[mi] = fmaf(w_, fmaf(-S[mi], e, a), S[mi]); // S += w*(a - S*e)
                o[(moff + mi) * DD] = S[mi];
            }
        }
        red[ll & 1][g][d] = racc;
        __syncthreads();
        if (g == 0)
            read_ws[(size_t)gp * DD + d] =
                red[ll & 1][0][d] + red[ll & 1][1][d] +
                red[ll & 1][2][d] + red[ll & 1][3][d];
    }
    __syncthreads();
    }
}

// ---------------------------------------------------------------------------
// Kernel 3: f = tanh([read,k] @ f_W^T + f_b); p = sigmoid(f . p_W + p_b).
// One block = 16 positions, 128 threads. (R2 version + rep loop)
// ---------------------------------------------------------------------------
__global__ __launch_bounds__(128) void k_fp(
    const int* __restrict__ q,
    const float* __restrict__ k_emb,
    const float* __restrict__ read_ws,
    const float* __restrict__ f_W, const float* __restrict__ f_b,
    const float* __restrict__ p_W, const float* __restrict__ p_b,
    float* __restrict__ out_p, int rep)
{
    __shared__ float cat[16][2 * DD];
    __shared__ float fv[16][DD];

    const int tid = threadIdx.x;
    const int p0  = blockIdx.x * 16;

    for (int rp = 0; rp < rep; ++rp) {

    // stage [read, k] rows (256 floats each) into LDS
    #pragma unroll
    for (int rr = 0; rr < 8; ++rr) {
        int idx = rr * 128 + tid;         // 0..1023 = 16 pos x 64 float4
        int pos = idx >> 6;
        int c4  = idx & 63;
        int gp  = p0 + pos;
        float4 val;
        if (c4 < 32) val = *(const float4*)(read_ws + (size_t)gp * DD + c4 * 4);
        else         val = *(const float4*)(k_emb + (size_t)q[gp] * DD + (c4 - 32) * 4);
        *(float4*)(&cat[pos][c4 * 4]) = val;
    }
    __syncthreads();

    // f: thread i computes f[pos][i] for all 16 positions
    const int i = tid;
    float acc[16];
    const float fb = f_b[i];
    #pragma unroll
    for (int p = 0; p < 16; ++p) acc[p] = fb;

    const float4* fw = (const float4*)(f_W + (size_t)i * (2 * DD));
    #pragma unroll 2
    for (int j4 = 0; j4 < 64; ++j4) {
        float4 wv = fw[j4];
        #pragma unroll
        for (int p = 0; p < 16; ++p) {
            const float* cp = &cat[p][j4 * 4];
            acc[p] = fmaf(wv.x, cp[0], acc[p]);
            acc[p] = fmaf(wv.y, cp[1], acc[p]);
            acc[p] = fmaf(wv.z, cp[2], acc[p]);
            acc[p] = fmaf(wv.w, cp[3], acc[p]);
        }
    }
    #pragma unroll
    for (int p = 0; p < 16; ++p) fv[p][i] = tanhf(acc[p]);
    __syncthreads();

    // p: 16 positions x 8 lanes each
    const int pos = tid >> 3;
    const int l8  = tid & 7;
    float partial = 0.f;
    #pragma unroll
    for (int ii = l8; ii < DD; ii += 8)
        partial = fmaf(fv[pos][ii], p_W[ii], partial);
    partial += __shfl_down(partial, 4, 64);
    partial += __shfl_down(partial, 2, 64);
    partial += __shfl_down(partial, 1, 64);
    if (l8 == 0)
        out_p[p0 + pos] = 1.f / (1.f + expf(-(partial + p_b[0])));
    __syncthreads();
    }
}

// ---------------------------------------------------------------------------
extern "C" void kernel_launch(void* const* d_in, const int* in_sizes, int n_in,
                              void* d_out, int out_size, void* d_ws, size_t ws_size,
                              hipStream_t stream)
{
    const int*   q     = (const int*)d_in[0];
    const int*   r     = (const int*)d_in[1];
    const float* k_emb = (const float*)d_in[2];
    const float* v_emb = (const float*)d_in[3];
    const float* Mk    = (const float*)d_in[4];
    const float* Mv0   = (const float*)d_in[5];
    const float* f_W   = (const float*)d_in[6];
    const float* f_b   = (const float*)d_in[7];
    const float* p_W   = (const float*)d_in[8];
    const float* p_b   = (const float*)d_in[9];
    const float* e_W   = (const float*)d_in[10];
    const float* e_b   = (const float*)d_in[11];
    const float* a_W   = (const float*)d_in[12];
    const float* a_b   = (const float*)d_in[13];

    float* out_p  = (float*)d_out;           // [B,L]
    float* out_Mv = out_p + NPOS;            // [B,L+1,M,D]

    float* w_ws    = (float*)d_ws;                         // NPOS*MM
    float* e_ws    = w_ws + (size_t)NPOS * MM;             // NPOS*DD
    float* a_ws    = e_ws + (size_t)NPOS * DD;             // NPOS*DD
    float* read_ws = a_ws + (size_t)NPOS * DD;             // NPOS*DD
    float* A_ws    = read_ws + (size_t)NPOS * DD;          // B*NC*MM*DD
    float* B_ws    = A_ws + (size_t)BB * NC * MM * DD;     // B*NC*MM*DD

    hipLaunchKernelGGL(k_wea, dim3(NPOS / 16), dim3(256), 0, stream,
                       q, r, k_emb, v_emb, Mk, e_W, e_b, a_W, a_b,
                       w_ws, e_ws, a_ws, REP_WEA);
    hipLaunchKernelGGL(k_scanA, dim3(BB * NC), dim3(512), 0, stream,
                       w_ws, e_ws, a_ws, A_ws, B_ws, REP_SCANA);
    hipLaunchKernelGGL(k_scanB, dim3((BB * MM * DD) / 256), dim3(256), 0, stream,
                       Mv0, A_ws, B_ws);
    hipLaunchKernelGGL(k_scanC, dim3(BB * NC), dim3(512), 0, stream,
                       A_ws, w_ws, e_ws, a_ws, read_ws, out_Mv, REP_SCANC);
    hipLaunchKernelGGL(k_fp, dim3(NPOS / 16), dim3(128), 0, stream,
                       q, k_emb, read_ws, f_W, f_b, p_W, p_b, out_p, REP_FP);
}

// Round 7
// 714.588 us; speedup vs baseline: 3.3858x; 3.3858x over previous
//
#include <hip/hip_runtime.h>
#include <math.h>

#define BB 64
#define LL 200
#define DD 128
#define MM 50
#define NQ 10000
#define NPOS (BB * LL)   // 12800
#define LC 20            // scan chunk length
#define NC 10            // number of chunks (LC*NC == LL)

// Diagnostic amplification (idempotent kernels only). This round: scanC x8.
#define REP_SCANA 1
#define REP_SCANC 8
#define REP_FP    1

__device__ __forceinline__ float dot4(float4 a, float4 b, float c) {
    return fmaf(a.x, b.x, fmaf(a.y, b.y, fmaf(a.z, b.z, fmaf(a.w, b.w, c))));
}

// ---------------------------------------------------------------------------
// Kernel 1 (REWRITE): fused w/e/a. Block = 64 positions, 256 threads, 4 waves.
// lanes = positions. Weight addresses are wave-uniform (s_load path, 1 line
// per instr), inputs k/v in LDS stride-129 (2-way bank = free). Outputs
// transposed through wave-private LDS buf for coalesced global stores.
// LDS: 8256 + 4352 floats = 50.4 KB -> 3 blocks/CU.
// ---------------------------------------------------------------------------
__global__ __launch_bounds__(256) void k_wea(
    const int* __restrict__ q, const int* __restrict__ r,
    const float* __restrict__ k_emb, const float* __restrict__ v_emb,
    const float* __restrict__ Mk,
    const float* __restrict__ e_W, const float* __restrict__ e_b,
    const float* __restrict__ a_W, const float* __restrict__ a_b,
    float* __restrict__ w_ws, float* __restrict__ e_ws, float* __restrict__ a_ws)
{
    __shared__ float kv[64 * 129];        // k (phase 1-2), then v (phase 4-5)
    __shared__ float aux[4 * 64 * 17];    // lg [64][53] (ph 2-4) / buf[w][64][17] (ph 5)
    float* lg = aux;

    const int tid  = threadIdx.x;
    const int p0   = blockIdx.x * 64;
    const int w    = tid >> 6;
    const int lane = tid & 63;

    // ---- phase 1: stage k rows (coalesced read, scalar LDS writes) ----
    #pragma unroll
    for (int it = 0; it < 8; ++it) {
        int idx = it * 256 + tid;            // 0..2047 = 64 pos x 32 float4
        int pos = idx >> 5, c4 = idx & 31;
        float4 kk = *(const float4*)(k_emb + (size_t)q[p0 + pos] * DD + c4 * 4);
        float* dst = &kv[pos * 129 + c4 * 4];
        dst[0] = kk.x; dst[1] = kk.y; dst[2] = kk.z; dst[3] = kk.w;
    }
    __syncthreads();

    // ---- phase 2: logits. wave w owns 13 m-rows (m0: 0,13,26,37; overlap benign) ----
    {
        const int m0 = __builtin_amdgcn_readfirstlane(w < 3 ? w * 13 : 37);
        const float4* MkR = (const float4*)Mk + (size_t)m0 * 32;
        float acc[13];
        #pragma unroll
        for (int s = 0; s < 13; ++s) acc[s] = 0.f;
        for (int j4 = 0; j4 < 32; ++j4) {
            const float* kp = &kv[lane * 129 + j4 * 4];
            float4 k4 = {kp[0], kp[1], kp[2], kp[3]};
            #pragma unroll
            for (int s = 0; s < 13; ++s)
                acc[s] = dot4(k4, MkR[s * 32 + j4], acc[s]);
        }
        #pragma unroll
        for (int s = 0; s < 13; ++s)
            lg[lane * 53 + m0 + s] = acc[s];
    }
    __syncthreads();

    // ---- phase 3: softmax per position (64 lanes, serial over M=50) ----
    if (tid < 64) {
        float* row = &lg[tid * 53];
        float mx = -INFINITY;
        for (int m = 0; m < MM; ++m) mx = fmaxf(mx, row[m]);
        float sum = 0.f;
        for (int m = 0; m < MM; ++m) {
            float e_ = expf(row[m] - mx);
            row[m] = e_;
            sum += e_;
        }
        row[50] = 1.f / sum;
    }
    __syncthreads();

    // ---- phase 4: w out (coalesced) + stage v over k ----
    for (int idx = tid; idx < 64 * MM; idx += 256) {
        int pos = idx / MM, m = idx - pos * MM;
        w_ws[(size_t)p0 * MM + idx] = lg[pos * 53 + m] * lg[pos * 53 + 50];
    }
    #pragma unroll
    for (int it = 0; it < 8; ++it) {
        int idx = it * 256 + tid;
        int pos = idx >> 5, c4 = idx & 31;
        int gp  = p0 + pos;
        int xi  = q[gp] + NQ * r[gp];
        float4 vv = *(const float4*)(v_emb + (size_t)xi * DD + c4 * 4);
        float* dst = &kv[pos * 129 + c4 * 4];
        dst[0] = vv.x; dst[1] = vv.y; dst[2] = vv.z; dst[3] = vv.w;
    }
    __syncthreads();

    // ---- phase 5: e/a. wave w owns output dims [w*32, w*32+32), two half-passes ----
    {
        const int i0 = __builtin_amdgcn_readfirstlane(w * 32);
        float* buf = &aux[w * 1088];                 // [64][17], wave-private
        const float4* eW4 = (const float4*)e_W;
        const float4* aW4 = (const float4*)a_W;

        for (int hp = 0; hp < 2; ++hp) {
            const int ib = i0 + hp * 16;
            float accE[16], accA[16];
            #pragma unroll
            for (int ii = 0; ii < 16; ++ii) { accE[ii] = 0.f; accA[ii] = 0.f; }

            for (int j4 = 0; j4 < 32; ++j4) {
                const float* vp = &kv[lane * 129 + j4 * 4];
                float4 v4 = {vp[0], vp[1], vp[2], vp[3]};
                #pragma unroll
                for (int ii = 0; ii < 16; ++ii) {
                    accE[ii] = dot4(v4, eW4[(size_t)(ib + ii) * 32 + j4], accE[ii]);
                    accA[ii] = dot4(v4, aW4[(size_t)(ib + ii) * 32 + j4], accA[ii]);
                }
            }

            // e: activation -> wave-private transpose buf -> coalesced store
            #pragma unroll
            for (int ii = 0; ii < 16; ++ii)
                buf[lane * 17 + ii] = 1.f / (1.f + expf(-(accE[ii] + e_b[ib + ii])));
            #pragma unroll
            for (int it = 0; it < 4; ++it) {
                int idx = it * 64 + lane;            // 0..255 = 64 pos x 4 q4
                int pp = idx >> 2, q4 = idx & 3;
                const float* bp = &buf[pp * 17 + q4 * 4];
                float4 o = {bp[0], bp[1], bp[2], bp[3]};
                *(float4*)(e_ws + (size_t)(p0 + pp) * DD + ib + q4 * 4) = o;
            }
            // a: same
            #pragma unroll
            for (int ii = 0; ii < 16; ++ii)
                buf[lane * 17 + ii] = tanhf(accA[ii] + a_b[ib + ii]);
            #pragma unroll
            for (int it = 0; it < 4; ++it) {
                int idx = it * 64 + lane;
                int pp = idx >> 2, q4 = idx & 3;
                const float* bp = &buf[pp * 17 + q4 * 4];
                float4 o = {bp[0], bp[1], bp[2], bp[3]};
                *(float4*)(a_ws + (size_t)(p0 + pp) * DD + ib + q4 * 4) = o;
            }
        }
    }
}

// ---------------------------------------------------------------------------
// Kernel 2a: per (b, chunk) affine composite S_out = A*S_in + B per (m,d).
// ---------------------------------------------------------------------------
__global__ __launch_bounds__(512) void k_scanA(
    const float* __restrict__ w_ws, const float* __restrict__ e_ws,
    const float* __restrict__ a_ws,
    float* __restrict__ A_ws, float* __restrict__ B_ws, int rep)
{
    __shared__ float w_lds[LC * MM];   // 4 KB

    const int b   = blockIdx.x / NC;
    const int c   = blockIdx.x % NC;
    const int tid = threadIdx.x;
    const int d   = tid & 127;
    const int g   = tid >> 7;
    int moff = g * 13; if (g == 3) moff = 38;
    const int mcnt = (g < 2) ? 13 : 12;

    for (int rp = 0; rp < rep; ++rp) {

    const float* wsrc = w_ws + ((size_t)b * LL + c * LC) * MM;  // contiguous
    for (int idx = tid; idx < LC * MM; idx += 512) w_lds[idx] = wsrc[idx];
    __syncthreads();

    float A[13], Bv[13];
    #pragma unroll
    for (int mi = 0; mi < 13; ++mi) { A[mi] = 1.f; Bv[mi] = 0.f; }

    for (int ll = 0; ll < LC; ++ll) {
        const int gp = b * LL + c * LC + ll;
        const float e = e_ws[(size_t)gp * DD + d];
        const float a = a_ws[(size_t)gp * DD + d];
        const float* wl = w_lds + ll * MM + moff;
        #pragma unroll
        for (int mi = 0; mi < 13; ++mi) {
            if (mi < mcnt) {
                float w_ = wl[mi];
                float cc = fmaf(-w_, e, 1.f);
                A[mi] *= cc;
                Bv[mi] = fmaf(Bv[mi], cc, w_ * a);
            }
        }
    }

    float* Ao = A_ws + ((size_t)b * NC + c) * MM * DD + (size_t)moff * DD + d;
    float* Bo = B_ws + ((size_t)b * NC + c) * MM * DD + (size_t)moff * DD + d;
    #pragma unroll
    for (int mi = 0; mi < 13; ++mi) {
        if (mi < mcnt) { Ao[mi * DD] = A[mi]; Bo[mi * DD] = Bv[mi]; }
    }
    __syncthreads();
    }
}

// ---------------------------------------------------------------------------
// Kernel 2b: sequential composition over chunks; entry states in-place.
// NOT idempotent -> never amplified.
// ---------------------------------------------------------------------------
__global__ __launch_bounds__(256) void k_scanB(
    const float* __restrict__ Mv0,
    float* __restrict__ A_ws,            // in: A, out: Sentry
    const float* __restrict__ B_ws)
{
    const int g  = blockIdx.x * 256 + threadIdx.x;   // 0 .. B*M*D-1
    const int d  = g & (DD - 1);
    const int md = g >> 7;
    const int m  = md % MM;
    const int b  = md / MM;

    float S = Mv0[m * DD + d];
    const size_t base = ((size_t)b * NC * MM + m) * DD + d;
    #pragma unroll
    for (int c = 0; c < NC; ++c) {
        const size_t off = base + (size_t)c * MM * DD;
        const float Ac = A_ws[off];
        const float Bc = B_ws[off];
        A_ws[off] = S;                     // entry state of chunk c
        S = fmaf(Ac, S, Bc);
    }
}

// ---------------------------------------------------------------------------
// Kernel 2c: replay scan per (b, chunk); writes all Mv states and read.
// ---------------------------------------------------------------------------
__global__ __launch_bounds__(512) void k_scanC(
    const float* __restrict__ Sentry,     // == A_ws after k_scanB
    const float* __restrict__ w_ws, const float* __restrict__ e_ws,
    const float* __restrict__ a_ws,
    float* __restrict__ read_ws, float* __restrict__ out_Mv, int rep)
{
    __shared__ float w_lds[LC * MM];      // 4 KB
    __shared__ float red[2][4][DD];       // 4 KB

    const int b   = blockIdx.x / NC;
    const int c   = blockIdx.x % NC;
    const int tid = threadIdx.x;
    const int d   = tid & 127;
    const int g   = tid >> 7;
    int moff = g * 13; if (g == 3) moff = 38;
    const int mcnt = (g < 2) ? 13 : 12;

    for (int rp = 0; rp < rep; ++rp) {

    const float* wsrc = w_ws + ((size_t)b * LL + c * LC) * MM;
    for (int idx = tid; idx < LC * MM; idx += 512) w_lds[idx] = wsrc[idx];

    float S[13];
    const float* Sp = Sentry + ((size_t)b * NC + c) * MM * DD + (size_t)moff * DD + d;
    #pragma unroll
    for (int mi = 0; mi < 13; ++mi)
        if (mi < mcnt) S[mi] = Sp[mi * DD];

    float* outb = out_Mv + (size_t)b * (LL + 1) * MM * DD;
    if (c == 0) {
        #pragma unroll
        for (int mi = 0; mi < 13; ++mi)
            if (mi < mcnt) outb[(moff + mi) * DD + d] = S[mi];  // init state
    }
    __syncthreads();

    for (int ll = 0; ll < LC; ++ll) {
        const int l  = c * LC + ll;
        const int gp = b * LL + l;
        const float e = e_ws[(size_t)gp * DD + d];
        const float a = a_ws[(size_t)gp * DD + d];
        const float* wl = w_lds + ll * MM + moff;

        float racc = 0.f;
        float* o = outb + (size_t)(l + 1) * MM * DD + d;
        #pragma unroll
        for (int mi = 0; mi < 13; ++mi) {
            if (mi < mcnt) {
                float w_ = wl[mi];
                racc = fmaf(w_, S[mi], racc);                // pre-update read
                S[mi] = fmaf(w_, fmaf(-S[mi], e, a), S[mi]); // S += w*(a - S*e)
                o[(moff + mi) * DD] = S[mi];
            }
        }
        red[ll & 1][g][d] = racc;
        __syncthreads();
        if (g == 0)
            read_ws[(size_t)gp * DD + d] =
                red[ll & 1][0][d] + red[ll & 1][1][d] +
                red[ll & 1][2][d] + red[ll & 1][3][d];
    }
    __syncthreads();
    }
}

// ---------------------------------------------------------------------------
// Kernel 3: f = tanh([read,k] @ f_W^T + f_b); p = sigmoid(f . p_W + p_b).
// One block = 16 positions, 128 threads. (R2 version)
// ---------------------------------------------------------------------------
__global__ __launch_bounds__(128) void k_fp(
    const int* __restrict__ q,
    const float* __restrict__ k_emb,
    const float* __restrict__ read_ws,
    const float* __restrict__ f_W, const float* __restrict__ f_b,
    const float* __restrict__ p_W, const float* __restrict__ p_b,
    float* __restrict__ out_p, int rep)
{
    __shared__ float cat[16][2 * DD];
    __shared__ float fv[16][DD];

    const int tid = threadIdx.x;
    const int p0  = blockIdx.x * 16;

    for (int rp = 0; rp < rep; ++rp) {

    #pragma unroll
    for (int rr = 0; rr < 8; ++rr) {
        int idx = rr * 128 + tid;         // 0..1023 = 16 pos x 64 float4
        int pos = idx >> 6;
        int c4  = idx & 63;
        int gp  = p0 + pos;
        float4 val;
        if (c4 < 32) val = *(const float4*)(read_ws + (size_t)gp * DD + c4 * 4);
        else         val = *(const float4*)(k_emb + (size_t)q[gp] * DD + (c4 - 32) * 4);
        *(float4*)(&cat[pos][c4 * 4]) = val;
    }
    __syncthreads();

    const int i = tid;
    float acc[16];
    const float fb = f_b[i];
    #pragma unroll
    for (int p = 0; p < 16; ++p) acc[p] = fb;

    const float4* fw = (const float4*)(f_W + (size_t)i * (2 * DD));
    #pragma unroll 2
    for (int j4 = 0; j4 < 64; ++j4) {
        float4 wv = fw[j4];
        #pragma unroll
        for (int p = 0; p < 16; ++p) {
            const float* cp = &cat[p][j4 * 4];
            acc[p] = fmaf(wv.x, cp[0], acc[p]);
            acc[p] = fmaf(wv.y, cp[1], acc[p]);
            acc[p] = fmaf(wv.z, cp[2], acc[p]);
            acc[p] = fmaf(wv.w, cp[3], acc[p]);
        }
    }
    #pragma unroll
    for (int p = 0; p < 16; ++p) fv[p][i] = tanhf(acc[p]);
    __syncthreads();

    const int pos = tid >> 3;
    const int l8  = tid & 7;
    float partial = 0.f;
    #pragma unroll
    for (int ii = l8; ii < DD; ii += 8)
        partial = fmaf(fv[pos][ii], p_W[ii], partial);
    partial += __shfl_down(partial, 4, 64);
    partial += __shfl_down(partial, 2, 64);
    partial += __shfl_down(partial, 1, 64);
    if (l8 == 0)
        out_p[p0 + pos] = 1.f / (1.f + expf(-(partial + p_b[0])));
    __syncthreads();
    }
}

// ---------------------------------------------------------------------------
extern "C" void kernel_launch(void* const* d_in, const int* in_sizes, int n_in,
                              void* d_out, int out_size, void* d_ws, size_t ws_size,
                              hipStream_t stream)
{
    const int*   q     = (const int*)d_in[0];
    const int*   r     = (const int*)d_in[1];
    const float* k_emb = (const float*)d_in[2];
    const float* v_emb = (const float*)d_in[3];
    const float* Mk    = (const float*)d_in[4];
    const float* Mv0   = (const float*)d_in[5];
    const float* f_W   = (const float*)d_in[6];
    const float* f_b   = (const float*)d_in[7];
    const float* p_W   = (const float*)d_in[8];
    const float* p_b   = (const float*)d_in[9];
    const float* e_W   = (const float*)d_in[10];
    const float* e_b   = (const float*)d_in[11];
    const float* a_W   = (const float*)d_in[12];
    const float* a_b   = (const float*)d_in[13];

    float* out_p  = (float*)d_out;           // [B,L]
    float* out_Mv = out_p + NPOS;            // [B,L+1,M,D]

    float* w_ws    = (float*)d_ws;                         // NPOS*MM
    float* e_ws    = w_ws + (size_t)NPOS * MM;             // NPOS*DD
    float* a_ws    = e_ws + (size_t)NPOS * DD;             // NPOS*DD
    float* read_ws = a_ws + (size_t)NPOS * DD;             // NPOS*DD
    float* A_ws    = read_ws + (size_t)NPOS * DD;          // B*NC*MM*DD
    float* B_ws    = A_ws + (size_t)BB * NC * MM * DD;     // B*NC*MM*DD

    hipLaunchKernelGGL(k_wea, dim3(NPOS / 64), dim3(256), 0, stream,
                       q, r, k_emb, v_emb, Mk, e_W, e_b, a_W, a_b,
                       w_ws, e_ws, a_ws);
    hipLaunchKernelGGL(k_scanA, dim3(BB * NC), dim3(512), 0, stream,
                       w_ws, e_ws, a_ws, A_ws, B_ws, REP_SCANA);
    hipLaunchKernelGGL(k_scanB, dim3((BB * MM * DD) / 256), dim3(256), 0, stream,
                       Mv0, A_ws, B_ws);
    hipLaunchKernelGGL(k_scanC, dim3(BB * NC), dim3(512), 0, stream,
                       A_ws, w_ws, e_ws, a_ws, read_ws, out_Mv, REP_SCANC);
    hipLaunchKernelGGL(k_fp, dim3(NPOS / 16), dim3(128), 0, stream,
                       q, k_emb, read_ws, f_W, f_b, p_W, p_b, out_p, REP_FP);
}

// Round 8
// 210.240 us; speedup vs baseline: 11.5081x; 3.3989x over previous
//
#include <hip/hip_runtime.h>
#include <math.h>

#define BB 64
#define LL 200
#define DD 128
#define MM 50
#define NQ 10000
#define NPOS (BB * LL)   // 12800
#define LC 20            // scan chunk length
#define NC 10            // number of chunks (LC*NC == LL)

__device__ __forceinline__ float dot4(float4 a, float4 b, float c) {
    return fmaf(a.x, b.x, fmaf(a.y, b.y, fmaf(a.z, b.z, fmaf(a.w, b.w, c))));
}

// ---------------------------------------------------------------------------
// Kernel 1a: w = softmax(k @ Mk^T). 64 positions/block (lane = position),
// 256 thr / 4 waves; wave w owns 13 m-rows (wave-uniform Mk loads).
// ---------------------------------------------------------------------------
__global__ __launch_bounds__(256) void k_w(
    const int* __restrict__ q, const float* __restrict__ k_emb,
    const float* __restrict__ Mk, float* __restrict__ w_ws)
{
    __shared__ float kv[64 * 129];
    __shared__ float lg[64 * 53 + 20];

    const int tid  = threadIdx.x;
    const int p0   = blockIdx.x * 64;
    const int w    = tid >> 6;
    const int lane = tid & 63;

    // stage k rows (coalesced read, scalar LDS writes, odd stride)
    #pragma unroll
    for (int it = 0; it < 8; ++it) {
        int idx = it * 256 + tid;            // 64 pos x 32 float4
        int pos = idx >> 5, c4 = idx & 31;
        float4 kk = *(const float4*)(k_emb + (size_t)q[p0 + pos] * DD + c4 * 4);
        float* dst = &kv[pos * 129 + c4 * 4];
        dst[0] = kk.x; dst[1] = kk.y; dst[2] = kk.z; dst[3] = kk.w;
    }
    __syncthreads();

    // logits (waves 2/3 overlap at m=37..38 with identical values: benign)
    {
        const int m0 = __builtin_amdgcn_readfirstlane(w < 3 ? w * 13 : 37);
        const float4* MkR = (const float4*)Mk + (size_t)m0 * 32;
        float acc[13];
        #pragma unroll
        for (int s = 0; s < 13; ++s) acc[s] = 0.f;
        for (int j4 = 0; j4 < 32; ++j4) {
            const float* kp = &kv[lane * 129 + j4 * 4];
            float4 k4 = {kp[0], kp[1], kp[2], kp[3]};
            #pragma unroll
            for (int s = 0; s < 13; ++s)
                acc[s] = dot4(k4, MkR[s * 32 + j4], acc[s]);
        }
        #pragma unroll
        for (int s = 0; s < 13; ++s)
            lg[lane * 53 + m0 + s] = acc[s];
    }
    __syncthreads();

    // softmax per position
    if (tid < 64) {
        float* row = &lg[tid * 53];
        float mx = -INFINITY;
        for (int m = 0; m < MM; ++m) mx = fmaxf(mx, row[m]);
        float sum = 0.f;
        for (int m = 0; m < MM; ++m) {
            float e_ = expf(row[m] - mx);
            row[m] = e_;
            sum += e_;
        }
        row[50] = 1.f / sum;
    }
    __syncthreads();

    // w out (coalesced)
    for (int idx = tid; idx < 64 * MM; idx += 256) {
        int pos = idx / MM, m = idx - pos * MM;
        w_ws[(size_t)p0 * MM + idx] = lg[pos * 53 + m] * lg[pos * 53 + 50];
    }
}

// ---------------------------------------------------------------------------
// Kernel 1b: e = sigmoid(v@e_W^T+e_b), a = tanh(v@a_W^T+a_b).
// 800 blocks = 200 pos-groups x 4 i-chunks; 256 thr; lane = position.
// Wave w owns 8 output dims -> weight addresses wave-uniform (1 line/instr).
// Transposed stores through wave-private LDS buf.
// ---------------------------------------------------------------------------
__global__ __launch_bounds__(256) void k_ea(
    const int* __restrict__ q, const int* __restrict__ r,
    const float* __restrict__ v_emb,
    const float* __restrict__ e_W, const float* __restrict__ e_b,
    const float* __restrict__ a_W, const float* __restrict__ a_b,
    float* __restrict__ e_ws, float* __restrict__ a_ws)
{
    __shared__ float vl[64 * 129];
    __shared__ float buf[4][64][9];

    const int tid  = threadIdx.x;
    const int pg   = blockIdx.x >> 2;
    const int ic   = blockIdx.x & 3;
    const int p0   = pg * 64;
    const int w    = tid >> 6;
    const int lane = tid & 63;

    #pragma unroll
    for (int it = 0; it < 8; ++it) {
        int idx = it * 256 + tid;
        int pos = idx >> 5, c4 = idx & 31;
        int gp  = p0 + pos;
        int xi  = q[gp] + NQ * r[gp];
        float4 vv = *(const float4*)(v_emb + (size_t)xi * DD + c4 * 4);
        float* dst = &vl[pos * 129 + c4 * 4];
        dst[0] = vv.x; dst[1] = vv.y; dst[2] = vv.z; dst[3] = vv.w;
    }
    __syncthreads();

    const int i0 = __builtin_amdgcn_readfirstlane(ic * 32 + w * 8);
    const float4* eW4 = (const float4*)e_W + (size_t)i0 * 32;
    const float4* aW4 = (const float4*)a_W + (size_t)i0 * 32;

    float accE[8], accA[8];
    #pragma unroll
    for (int ii = 0; ii < 8; ++ii) { accE[ii] = 0.f; accA[ii] = 0.f; }

    for (int j4 = 0; j4 < 32; ++j4) {
        const float* vp = &vl[lane * 129 + j4 * 4];
        float4 v4 = {vp[0], vp[1], vp[2], vp[3]};
        #pragma unroll
        for (int ii = 0; ii < 8; ++ii) {
            accE[ii] = dot4(v4, eW4[ii * 32 + j4], accE[ii]);
            accA[ii] = dot4(v4, aW4[ii * 32 + j4], accA[ii]);
        }
    }

    // e: activation -> wave-private transpose buf -> coalesced-ish store
    #pragma unroll
    for (int ii = 0; ii < 8; ++ii)
        buf[w][lane][ii] = 1.f / (1.f + expf(-(accE[ii] + e_b[i0 + ii])));
    #pragma unroll
    for (int it = 0; it < 2; ++it) {
        int idx = it * 64 + lane;            // 64 pos x 2 q4
        int pp = idx >> 1, q4 = idx & 1;
        const float* bp = &buf[w][pp][q4 * 4];
        float4 o = {bp[0], bp[1], bp[2], bp[3]};
        *(float4*)(e_ws + (size_t)(p0 + pp) * DD + i0 + q4 * 4) = o;
    }
    // a: same
    #pragma unroll
    for (int ii = 0; ii < 8; ++ii)
        buf[w][lane][ii] = tanhf(accA[ii] + a_b[i0 + ii]);
    #pragma unroll
    for (int it = 0; it < 2; ++it) {
        int idx = it * 64 + lane;
        int pp = idx >> 1, q4 = idx & 1;
        const float* bp = &buf[w][pp][q4 * 4];
        float4 o = {bp[0], bp[1], bp[2], bp[3]};
        *(float4*)(a_ws + (size_t)(p0 + pp) * DD + i0 + q4 * 4) = o;
    }
}

// ---------------------------------------------------------------------------
// Kernel 2a: per (b, chunk) affine composite S_out = A*S_in + B per (m,d).
// ---------------------------------------------------------------------------
__global__ __launch_bounds__(512) void k_scanA(
    const float* __restrict__ w_ws, const float* __restrict__ e_ws,
    const float* __restrict__ a_ws,
    float* __restrict__ A_ws, float* __restrict__ B_ws)
{
    __shared__ float w_lds[LC * MM];   // 4 KB

    const int b   = blockIdx.x / NC;
    const int c   = blockIdx.x % NC;
    const int tid = threadIdx.x;
    const int d   = tid & 127;
    const int g   = tid >> 7;
    int moff = g * 13; if (g == 3) moff = 38;
    const int mcnt = (g < 2) ? 13 : 12;

    const float* wsrc = w_ws + ((size_t)b * LL + c * LC) * MM;  // contiguous
    for (int idx = tid; idx < LC * MM; idx += 512) w_lds[idx] = wsrc[idx];
    __syncthreads();

    float A[13], Bv[13];
    #pragma unroll
    for (int mi = 0; mi < 13; ++mi) { A[mi] = 1.f; Bv[mi] = 0.f; }

    for (int ll = 0; ll < LC; ++ll) {
        const int gp = b * LL + c * LC + ll;
        const float e = e_ws[(size_t)gp * DD + d];
        const float a = a_ws[(size_t)gp * DD + d];
        const float* wl = w_lds + ll * MM + moff;
        #pragma unroll
        for (int mi = 0; mi < 13; ++mi) {
            if (mi < mcnt) {
                float w_ = wl[mi];
                float cc = fmaf(-w_, e, 1.f);
                A[mi] *= cc;
                Bv[mi] = fmaf(Bv[mi], cc, w_ * a);
            }
        }
    }

    float* Ao = A_ws + ((size_t)b * NC + c) * MM * DD + (size_t)moff * DD + d;
    float* Bo = B_ws + ((size_t)b * NC + c) * MM * DD + (size_t)moff * DD + d;
    #pragma unroll
    for (int mi = 0; mi < 13; ++mi) {
        if (mi < mcnt) { Ao[mi * DD] = A[mi]; Bo[mi * DD] = Bv[mi]; }
    }
}

// ---------------------------------------------------------------------------
// Kernel 2b: sequential composition over chunks; entry states in-place.
// ---------------------------------------------------------------------------
__global__ __launch_bounds__(256) void k_scanB(
    const float* __restrict__ Mv0,
    float* __restrict__ A_ws,            // in: A, out: Sentry
    const float* __restrict__ B_ws)
{
    const int g  = blockIdx.x * 256 + threadIdx.x;   // 0 .. B*M*D-1
    const int d  = g & (DD - 1);
    const int md = g >> 7;
    const int m  = md % MM;
    const int b  = md / MM;

    float S = Mv0[m * DD + d];
    const size_t base = ((size_t)b * NC * MM + m) * DD + d;
    #pragma unroll
    for (int c = 0; c < NC; ++c) {
        const size_t off = base + (size_t)c * MM * DD;
        const float Ac = A_ws[off];
        const float Bc = B_ws[off];
        A_ws[off] = S;                     // entry state of chunk c
        S = fmaf(Ac, S, Bc);
    }
}

// ---------------------------------------------------------------------------
// Kernel 2c: replay scan per (b, chunk); writes all Mv states and read.
// ---------------------------------------------------------------------------
__global__ __launch_bounds__(512) void k_scanC(
    const float* __restrict__ Sentry,     // == A_ws after k_scanB
    const float* __restrict__ w_ws, const float* __restrict__ e_ws,
    const float* __restrict__ a_ws,
    float* __restrict__ read_ws, float* __restrict__ out_Mv)
{
    __shared__ float w_lds[LC * MM];      // 4 KB
    __shared__ float red[2][4][DD];       // 4 KB

    const int b   = blockIdx.x / NC;
    const int c   = blockIdx.x % NC;
    const int tid = threadIdx.x;
    const int d   = tid & 127;
    const int g   = tid >> 7;
    int moff = g * 13; if (g == 3) moff = 38;
    const int mcnt = (g < 2) ? 13 : 12;

    const float* wsrc = w_ws + ((size_t)b * LL + c * LC) * MM;
    for (int idx = tid; idx < LC * MM; idx += 512) w_lds[idx] = wsrc[idx];

    float S[13];
    const float* Sp = Sentry + ((size_t)b * NC + c) * MM * DD + (size_t)moff * DD + d;
    #pragma unroll
    for (int mi = 0; mi < 13; ++mi)
        if (mi < mcnt) S[mi] = Sp[mi * DD];

    float* outb = out_Mv + (size_t)b * (LL + 1) * MM * DD;
    if (c == 0) {
        #pragma unroll
        for (int mi = 0; mi < 13; ++mi)
            if (mi < mcnt) outb[(moff + mi) * DD + d] = S[mi];  // init state
    }
    __syncthreads();

    for (int ll = 0; ll < LC; ++ll) {
        const int l  = c * LC + ll;
        const int gp = b * LL + l;
        const float e = e_ws[(size_t)gp * DD + d];
        const float a = a_ws[(size_t)gp * DD + d];
        const float* wl = w_lds + ll * MM + moff;

        float racc = 0.f;
        float* o = outb + (size_t)(l + 1) * MM * DD + d;
        #pragma unroll
        for (int mi = 0; mi < 13; ++mi) {
            if (mi < mcnt) {
                float w_ = wl[mi];
                racc = fmaf(w_, S[mi], racc);                // pre-update read
                S[mi] = fmaf(w_, fmaf(-S[mi], e, a), S[mi]); // S += w*(a - S*e)
                o[(moff + mi) * DD] = S[mi];
            }
        }
        red[ll & 1][g][d] = racc;
        __syncthreads();
        if (g == 0)
            read_ws[(size_t)gp * DD + d] =
                red[ll & 1][0][d] + red[ll & 1][1][d] +
                red[ll & 1][2][d] + red[ll & 1][3][d];
    }
}

// ---------------------------------------------------------------------------
// Kernel 3a: partial p contributions. 800 blocks = 200 pos-groups x 4
// i-chunks; lane = position; wave w owns 8 f-outputs (uniform f_W loads).
// p_part[ic][pos] = sum_{i in chunk} tanh(f_i) * p_W[i].
// ---------------------------------------------------------------------------
__global__ __launch_bounds__(256) void k_f(
    const int* __restrict__ q,
    const float* __restrict__ k_emb,
    const float* __restrict__ read_ws,
    const float* __restrict__ f_W, const float* __restrict__ f_b,
    const float* __restrict__ p_W,
    float* __restrict__ p_part)
{
    __shared__ float cl[64 * 261];       // [read(128) | k(128)], odd stride
    __shared__ float red[4][64];

    const int tid  = threadIdx.x;
    const int pg   = blockIdx.x >> 2;
    const int ic   = blockIdx.x & 3;
    const int p0   = pg * 64;
    const int w    = tid >> 6;
    const int lane = tid & 63;

    #pragma unroll
    for (int it = 0; it < 16; ++it) {
        int idx = it * 256 + tid;        // 64 pos x 64 float4
        int pos = idx >> 6, c4 = idx & 63;
        int gp  = p0 + pos;
        float4 val;
        if (c4 < 32) val = *(const float4*)(read_ws + (size_t)gp * DD + c4 * 4);
        else         val = *(const float4*)(k_emb + (size_t)q[gp] * DD + (c4 - 32) * 4);
        float* dst = &cl[pos * 261 + c4 * 4];
        dst[0] = val.x; dst[1] = val.y; dst[2] = val.z; dst[3] = val.w;
    }
    __syncthreads();

    const int i0 = __builtin_amdgcn_readfirstlane(ic * 32 + w * 8);
    const float4* fW4 = (const float4*)f_W + (size_t)i0 * 64;

    float acc[8];
    #pragma unroll
    for (int ii = 0; ii < 8; ++ii) acc[ii] = 0.f;

    for (int j4 = 0; j4 < 64; ++j4) {
        const float* cp = &cl[lane * 261 + j4 * 4];
        float4 c4v = {cp[0], cp[1], cp[2], cp[3]};
        #pragma unroll
        for (int ii = 0; ii < 8; ++ii)
            acc[ii] = dot4(c4v, fW4[ii * 64 + j4], acc[ii]);
    }

    float pp = 0.f;
    #pragma unroll
    for (int ii = 0; ii < 8; ++ii)
        pp = fmaf(tanhf(acc[ii] + f_b[i0 + ii]), p_W[i0 + ii], pp);
    red[w][lane] = pp;
    __syncthreads();

    if (tid < 64)
        p_part[(size_t)ic * NPOS + p0 + tid] =
            red[0][tid] + red[1][tid] + red[2][tid] + red[3][tid];
}

// ---------------------------------------------------------------------------
// Kernel 3b: p = sigmoid(sum of 4 partials + p_b).
// ---------------------------------------------------------------------------
__global__ __launch_bounds__(256) void k_p(
    const float* __restrict__ p_part, const float* __restrict__ p_b,
    float* __restrict__ out_p)
{
    const int gidx = blockIdx.x * 256 + threadIdx.x;
    if (gidx < NPOS) {
        float s = p_part[gidx] + p_part[NPOS + gidx] +
                  p_part[2 * NPOS + gidx] + p_part[3 * NPOS + gidx] + p_b[0];
        out_p[gidx] = 1.f / (1.f + expf(-s));
    }
}

// ---------------------------------------------------------------------------
extern "C" void kernel_launch(void* const* d_in, const int* in_sizes, int n_in,
                              void* d_out, int out_size, void* d_ws, size_t ws_size,
                              hipStream_t stream)
{
    const int*   q     = (const int*)d_in[0];
    const int*   r     = (const int*)d_in[1];
    const float* k_emb = (const float*)d_in[2];
    const float* v_emb = (const float*)d_in[3];
    const float* Mk    = (const float*)d_in[4];
    const float* Mv0   = (const float*)d_in[5];
    const float* f_W   = (const float*)d_in[6];
    const float* f_b   = (const float*)d_in[7];
    const float* p_W   = (const float*)d_in[8];
    const float* p_b   = (const float*)d_in[9];
    const float* e_W   = (const float*)d_in[10];
    const float* e_b   = (const float*)d_in[11];
    const float* a_W   = (const float*)d_in[12];
    const float* a_b   = (const float*)d_in[13];

    float* out_p  = (float*)d_out;           // [B,L]
    float* out_Mv = out_p + NPOS;            // [B,L+1,M,D]

    float* w_ws    = (float*)d_ws;                         // NPOS*MM
    float* e_ws    = w_ws + (size_t)NPOS * MM;             // NPOS*DD
    float* a_ws    = e_ws + (size_t)NPOS * DD;             // NPOS*DD
    float* read_ws = a_ws + (size_t)NPOS * DD;             // NPOS*DD
    float* A_ws    = read_ws + (size_t)NPOS * DD;          // B*NC*MM*DD
    float* B_ws    = A_ws + (size_t)BB * NC * MM * DD;     // B*NC*MM*DD
    float* p_part  = B_ws + (size_t)BB * NC * MM * DD;     // 4*NPOS

    hipLaunchKernelGGL(k_w, dim3(NPOS / 64), dim3(256), 0, stream,
                       q, k_emb, Mk, w_ws);
    hipLaunchKernelGGL(k_ea, dim3(4 * NPOS / 64), dim3(256), 0, stream,
                       q, r, v_emb, e_W, e_b, a_W, a_b, e_ws, a_ws);
    hipLaunchKernelGGL(k_scanA, dim3(BB * NC), dim3(512), 0, stream,
                       w_ws, e_ws, a_ws, A_ws, B_ws);
    hipLaunchKernelGGL(k_scanB, dim3((BB * MM * DD) / 256), dim3(256), 0, stream,
                       Mv0, A_ws, B_ws);
    hipLaunchKernelGGL(k_scanC, dim3(BB * NC), dim3(512), 0, stream,
                       A_ws, w_ws, e_ws, a_ws, read_ws, out_Mv);
    hipLaunchKernelGGL(k_f, dim3(4 * NPOS / 64), dim3(256), 0, stream,
                       q, k_emb, read_ws, f_W, f_b, p_W, p_part);
    hipLaunchKernelGGL(k_p, dim3((NPOS + 255) / 256), dim3(256), 0, stream,
                       p_part, p_b, out_p);
}